// Round 8
// baseline (425.761 us; speedup 1.0000x reference)
//
#include <hip/hip_runtime.h>

// HierarchicalLTI2: 32-layer cascade of 64-dim LTI blocks, T=8192.
// Per-layer FIR truncation at J=16 taps, each layer = GEMM (M=8192,N=64,K=1024)
// via implicit im2col, f16 MFMA fp32-acc.
// R10: ladder fit {R0,R5,R6,R9} -> launch F~1us, serial phase P~8us (32 phases
// in every variant). Phase floor is ~1.5us -> latency exposure at 1 block/CU.
// A/B: FD1 (minimum work, 16384 units), 16-row tiles, grid 512 = 2 blocks/CU,
// 4-deep B prefetch. prep_build (R9, verified) + y_final (R6, verified) kept.
// R8 confound removed (no fused-halo extra work this time).

#define LYR 32
#define NO  64
#define TSEQ 8192
#define JT  16
#define KD  (JT*NO)              // 1024
#define PROWS (TSEQ+JT)          // 8208
#define PBUF ((size_t)PROWS*NO)  // 525312 elements (f16)

typedef _Float16 h16;
typedef _Float16 h16x8 __attribute__((ext_vector_type(8)));
typedef float    f32x4 __attribute__((ext_vector_type(4)));

// ---- prep_build: one launch replacing prep + build + castK (verified R9) ---
// blocks 0..31: build layer b's K chain: K_0 = (b? Bl[b-1] : B0);
//   K_j = A_b * K_{j-1}, j=1..15 (f32 in LDS), each slice cast to kt
//   kt[b][n][(15-j)*64 + m].
// blocks 32..543: zero pads (33 buffers), cast u + C.
__global__ __launch_bounds__(256) void prep_build(
    const float* __restrict__ u, const float* __restrict__ B0,
    const float* __restrict__ Bl, const float* __restrict__ Cst,
    const float* __restrict__ Ast,
    h16* __restrict__ pall, h16* __restrict__ ccast, h16* __restrict__ kt)
{
    __shared__ float sm[3*64*68];            // 52,224 B
    const int tid = threadIdx.x;

    if (blockIdx.x < 32) {
        const int layer = blockIdx.x;
        float* la = sm;                      // A_layer
        float* kc = sm + 64*68;              // K_cur
        float* kn = sm + 2*64*68;            // K_next
        const float* k0 = (layer == 0) ? B0 : (Bl + (size_t)(layer-1)*4096);
        const float* Aw = Ast + (size_t)layer*4096;
        for (int e = tid; e < 4096; e += 256) {
            int r = e >> 6, c = e & 63;
            kc[r*68 + c] = k0[e];
            la[r*68 + c] = Aw[e];
        }
        __syncthreads();
        // write jp=15 slice (K_0)
        {
            size_t kb = (size_t)layer*65536 + 15*64;
            for (int e2 = tid; e2 < 1024; e2 += 256) {
                int n = e2 >> 4, c4 = (e2 & 15) << 2;
                h16 o4[4];
                #pragma unroll
                for (int t = 0; t < 4; t++) o4[t] = (h16)kc[n*68 + c4 + t];
                *(int2*)&kt[kb + (size_t)n*1024 + c4] = *(int2*)&o4[0];
            }
        }
        const int r0 = (tid >> 4) << 2;
        const int c0 = (tid & 15) << 2;
        for (int j = 1; j <= 15; j++) {
            float acc[4][4] = {};
            for (int k = 0; k < 64; k++) {
                float a0 = la[(r0+0)*68 + k];
                float a1 = la[(r0+1)*68 + k];
                float a2 = la[(r0+2)*68 + k];
                float a3 = la[(r0+3)*68 + k];
                f32x4 bv = *(const f32x4*)&kc[k*68 + c0];
                #pragma unroll
                for (int jj = 0; jj < 4; jj++) {
                    acc[0][jj] += a0*bv[jj]; acc[1][jj] += a1*bv[jj];
                    acc[2][jj] += a2*bv[jj]; acc[3][jj] += a3*bv[jj];
                }
            }
            size_t kb = (size_t)layer*65536 + (size_t)(15 - j)*64;
            #pragma unroll
            for (int i2 = 0; i2 < 4; i2++) {
                f32x4 o; o[0]=acc[i2][0]; o[1]=acc[i2][1]; o[2]=acc[i2][2]; o[3]=acc[i2][3];
                *(f32x4*)&kn[(r0+i2)*68 + c0] = o;
                h16 o4[4];
                #pragma unroll
                for (int t = 0; t < 4; t++) o4[t] = (h16)acc[i2][t];
                *(int2*)&kt[kb + (size_t)(r0+i2)*1024 + c0] = *(int2*)&o4[0];
            }
            __syncthreads();
            float* tmp = kc; kc = kn; kn = tmp;
        }
        return;
    }

    // ---- prep section (512 blocks) ----
    const int n_pad0 = JT*NO;            // 1024
    const int n_u    = TSEQ*NO;          // 524288
    const int n_c    = LYR*NO*NO;        // 131072
    const int n_zp   = 32*JT*NO;         // 32768 (pads of buffers 1..32)
    const int total8 = (n_pad0 + n_u + n_c + n_zp) >> 3;   // 86,144
    int idx8 = (blockIdx.x - 32)*256 + tid;
    const int4 zero4 = make_int4(0,0,0,0);
    for (; idx8 < total8; idx8 += 512*256) {
        int e = idx8 << 3;
        if (e < n_pad0) { *(int4*)&pall[e] = zero4; continue; }
        e -= n_pad0;
        if (e < n_u) {
            f32x4 f0 = *(const f32x4*)&u[e];
            f32x4 f1 = *(const f32x4*)&u[e+4];
            h16 ov[8];
            #pragma unroll
            for (int j = 0; j < 4; j++) { ov[j] = (h16)f0[j]; ov[4+j] = (h16)f1[j]; }
            *(int4*)&pall[n_pad0 + e] = *(int4*)&ov[0];
            continue;
        }
        e -= n_u;
        if (e < n_c) {
            f32x4 f0 = *(const f32x4*)&Cst[e];
            f32x4 f1 = *(const f32x4*)&Cst[e+4];
            h16 ov[8];
            #pragma unroll
            for (int j = 0; j < 4; j++) { ov[j] = (h16)f0[j]; ov[4+j] = (h16)f1[j]; }
            *(int4*)&ccast[e] = *(int4*)&ov[0];
            continue;
        }
        e -= n_c;
        int b = e >> 10;                 // buffer-1 index 0..31
        int off = e & 1023;
        *(int4*)&pall[(size_t)(b+1)*PBUF + off] = zero4;
    }
}

// ---- stage1: one layer, one 16-row output tile per block, grid 512 ---------
// 2 blocks/CU (8 waves/CU) for latency hiding. GEMM M=16, N=64, K=1024,
// split-K4 across waves, 4-deep B prefetch, 2-deep A (LDS).
__global__ __launch_bounds__(256, 2) void stage1(
    h16* pall, const h16* __restrict__ kt, int i0)
{
    __shared__ __align__(16) h16   win[32*72];       //  4,608 B
    __shared__ __align__(16) float red[2*16*68];     //  8,704 B
    const int tid = threadIdx.x;
    const size_t t0 = (size_t)blockIdx.x * 16;

    // input: padded rows t0 .. t0+31 of buffer i0 (output padded rows
    // JT+t0..JT+t0+15; out row w reads win rows w..w+15, win[0]=padded t0)
    const h16* pin = pall + (size_t)i0*PBUF;
    for (int e = tid; e < 32*8; e += 256) {
        int rr = e >> 3, cc = e & 7;
        *(int4*)&win[rr*72 + cc*8] = *(const int4*)&pin[(t0 + rr)*64 + cc*8];
    }
    __syncthreads();

    const int wv = tid >> 6, lane = tid & 63, r = lane & 15, q = lane >> 4;
    const h16* abase = &win[(r + wv*4)*72 + q*8];
    const h16* bbase = kt + (size_t)i0*NO*KD + (size_t)r*KD + wv*256 + q*8;
#define LDA1(ls) (*(const h16x8*)(abase + ((ls)>>1)*72 + ((ls)&1)*32))
#define LDB1(c, ls) (*(const h16x8*)(bbase + (c)*(16*KD) + (ls)*32))
    f32x4 acc[4] = {};
    h16x8 a[2], b[4][4];
    a[0] = LDA1(0); a[1] = LDA1(1);
    #pragma unroll
    for (int ls = 0; ls < 4; ls++)
        #pragma unroll
        for (int c = 0; c < 4; c++) b[ls][c] = LDB1(c, ls);
    #pragma unroll
    for (int ls = 0; ls < 8; ls++) {
        h16x8 ca = a[ls&1], cb[4];
        #pragma unroll
        for (int c = 0; c < 4; c++) cb[c] = b[ls&3][c];
        if (ls < 6) a[ls&1] = LDA1(ls+2);
        if (ls < 4) {
            #pragma unroll
            for (int c = 0; c < 4; c++) b[ls&3][c] = LDB1(c, ls+4);
        }
        #pragma unroll
        for (int c = 0; c < 4; c++)
            acc[c] = __builtin_amdgcn_mfma_f32_16x16x32_f16(ca, cb[c], acc[c], 0,0,0);
    }
#undef LDA1
#undef LDB1
    // split-K reduction: waves 2,3 write; waves 0,1 add; combine + store.
    if (wv >= 2) {
        float* myred = red + (size_t)(wv-2)*(16*68);
        #pragma unroll
        for (int c = 0; c < 4; c++)
            #pragma unroll
            for (int g = 0; g < 4; g++)
                myred[(q*4 + g)*68 + c*16 + r] = acc[c][g];
    }
    __syncthreads();
    if (wv < 2) {
        float* myred = red + (size_t)wv*(16*68);
        #pragma unroll
        for (int c = 0; c < 4; c++)
            #pragma unroll
            for (int g = 0; g < 4; g++)
                myred[(q*4 + g)*68 + c*16 + r] += acc[c][g];
    }
    __syncthreads();
    int orow = tid >> 4, c4 = (tid & 15) << 2;
    f32x4 u0 = *(const f32x4*)&red[orow*68 + c4];
    f32x4 v0 = *(const f32x4*)&red[16*68 + orow*68 + c4];
    u0 += v0;
    h16 o4[4];
    #pragma unroll
    for (int j = 0; j < 4; j++) o4[j] = (h16)u0[j];
    h16* gout = pall + (size_t)(i0+1)*PBUF + (JT + t0)*64;
    *(int2*)&gout[(size_t)orow*64 + c4] = *(int2*)&o4[0];
}

// ---- y_final: Y = sum_i X^(i) C_i^T, 32-row tiles, split-K4, 4-deep pf -----
// (verbatim from verified R6)
__global__ __launch_bounds__(256, 2) void y_final(
    const h16* __restrict__ pall, const h16* __restrict__ ccast,
    float* __restrict__ out)
{
    __shared__ __align__(16) float red[2*32*68];
    int tid = threadIdx.x;
    size_t t0 = (size_t)blockIdx.x * 32;
    int wv = tid >> 6, lane = tid & 63, r = lane & 15, q = lane >> 4;
    const h16* abase = pall + (size_t)(wv*8 + 1)*PBUF + (JT + t0 + r)*64 + q*8;
    const h16* bbase = ccast + (size_t)(wv*8)*4096 + (size_t)r*64 + q*8;
#define LDA2(s, ls) (*(const h16x8*)(abase + (size_t)((ls)>>1)*PBUF + (s)*(16*64) + ((ls)&1)*32))
#define LDB2(c, ls) (*(const h16x8*)(bbase + ((ls)>>1)*4096 + (c)*(16*64) + ((ls)&1)*32))
    f32x4 acc[2][4] = {};
    h16x8 a[4][2], b[4][4];
    #pragma unroll
    for (int ls = 0; ls < 4; ls++) {
        #pragma unroll
        for (int s = 0; s < 2; s++) a[ls][s] = LDA2(s, ls);
        #pragma unroll
        for (int c = 0; c < 4; c++) b[ls][c] = LDB2(c, ls);
    }
    #pragma unroll
    for (int ls = 0; ls < 16; ls++) {
        h16x8 ca[2], cb[4];
        #pragma unroll
        for (int s = 0; s < 2; s++) ca[s] = a[ls&3][s];
        #pragma unroll
        for (int c = 0; c < 4; c++) cb[c] = b[ls&3][c];
        if (ls < 12) {
            #pragma unroll
            for (int s = 0; s < 2; s++) a[ls&3][s] = LDA2(s, ls+4);
            #pragma unroll
            for (int c = 0; c < 4; c++) b[ls&3][c] = LDB2(c, ls+4);
        }
        #pragma unroll
        for (int s = 0; s < 2; s++)
            #pragma unroll
            for (int c = 0; c < 4; c++)
                acc[s][c] = __builtin_amdgcn_mfma_f32_16x16x32_f16(ca[s], cb[c], acc[s][c], 0,0,0);
    }
#undef LDA2
#undef LDB2
    if (wv >= 2) {
        float* myred = red + (size_t)(wv-2)*(32*68);
        #pragma unroll
        for (int s = 0; s < 2; s++)
            #pragma unroll
            for (int c = 0; c < 4; c++)
                #pragma unroll
                for (int g = 0; g < 4; g++)
                    myred[(s*16 + q*4 + g)*68 + c*16 + r] = acc[s][c][g];
    }
    __syncthreads();
    if (wv < 2) {
        float* myred = red + (size_t)wv*(32*68);
        #pragma unroll
        for (int s = 0; s < 2; s++)
            #pragma unroll
            for (int c = 0; c < 4; c++)
                #pragma unroll
                for (int g = 0; g < 4; g++)
                    myred[(s*16 + q*4 + g)*68 + c*16 + r] += acc[s][c][g];
    }
    __syncthreads();
    int orow = tid >> 3, cb2 = (tid & 7) << 3;
    f32x4 u0 = *(const f32x4*)&red[orow*68 + cb2];
    f32x4 u1 = *(const f32x4*)&red[orow*68 + cb2 + 4];
    f32x4 v0 = *(const f32x4*)&red[32*68 + orow*68 + cb2];
    f32x4 v1 = *(const f32x4*)&red[32*68 + orow*68 + cb2 + 4];
    u0 += v0; u1 += v1;
    size_t obase = (t0 + orow)*64 + cb2;
    *(f32x4*)&out[obase]     = u0;
    *(f32x4*)&out[obase + 4] = u1;
}

extern "C" void kernel_launch(void* const* d_in, const int* in_sizes, int n_in,
                              void* d_out, int out_size, void* d_ws, size_t ws_size,
                              hipStream_t stream)
{
    const float* u   = (const float*)d_in[0];
    const float* Ast = (const float*)d_in[1];
    const float* B0  = (const float*)d_in[2];
    const float* Bl  = (const float*)d_in[3];
    const float* Cst = (const float*)d_in[4];
    float* out = (float*)d_out;
    (void)in_sizes; (void)n_in; (void)out_size; (void)ws_size;

    char* ws = (char*)d_ws;
    const size_t PBUF_BYTES = PBUF*sizeof(h16);            // 1,050,624
    h16*   pall  = (h16*)ws;                               // 33 buffers
    h16*   ccast = (h16*)(ws + 33*PBUF_BYTES);             // 256 KiB
    h16*   kt    = (h16*)(ws + 33*PBUF_BYTES + 262144);    // 4 MiB

    prep_build<<<544, 256, 0, stream>>>(u, B0, Bl, Cst, Ast, pall, ccast, kt);
    for (int i = 0; i < LYR; i++) {
        stage1<<<TSEQ/16, 256, 0, stream>>>(pall, kt, i);
    }
    y_final<<<TSEQ/32, 256, 0, stream>>>(pall, ccast, out);
}

// Round 9
// 347.623 us; speedup vs baseline: 1.2248x; 1.2248x over previous
//
#include <hip/hip_runtime.h>

// HierarchicalLTI2: 32-layer cascade of 64-dim LTI blocks, T=8192.
// R11: serial-depth restructure. Evidence (R0/R5/R6/R8/R9/R10): every variant
// has 32 serial GEMM phases at ~6-8us each regardless of tiling/TLP/prefetch.
// Fix: compose 4 layers into one FIR (taps d=4..64, truncated to d<=32 since
// |tap| ~ 0.4^d; error ~1e-11). Same FLOPs as 4 layers (no halo recompute).
// y folded into stages: D^(g)_d = sum_r C_{4g+r} comp(r)_d applied to the same
// A-window (N=128). Serial phases 33 -> 13:
//   prep_build | compose2 | compose3 | compose4 | castD | 8x stage.
// Compose = 64x64x64 MFMA products (f16 in, f32 acc); P2/P3 stored TRANSPOSED
// (always B-operands); D accumulated by f32 atomicAdd into Dacc.

#define LYR 32
#define NO  64
#define TSEQ 8192
#define PAD 32
#define PR2 (TSEQ+PAD)            // 8224
#define PB2 ((size_t)PR2*NO)      // 526336 elems (h16)
#define KQ  2048                  // stage K = 32 taps * 64

typedef _Float16 h16;
typedef _Float16 h16x8 __attribute__((ext_vector_type(8)));
typedef float    f32x4 __attribute__((ext_vector_type(4)));

#define MFMA16(a,b,c) __builtin_amdgcn_mfma_f32_16x16x32_f16((a),(b),(c),0,0,0)

// ---- prep_build -------------------------------------------------------------
// blocks 0..31: layer singles T^(l)_j = A^j B (f32 chain in LDS), cast to
//   SN[l][j][n][m] (natural) and ST[l][j][m][n] (transposed), j=0..15.
// blocks 32..543: zero xq pads, cast u -> xq[0], cast C -> ccast,
//   zero ktq, zero Dacc.
__global__ __launch_bounds__(256) void prep_build(
    const float* __restrict__ u, const float* __restrict__ B0,
    const float* __restrict__ Bl, const float* __restrict__ Cst,
    const float* __restrict__ Ast,
    h16* __restrict__ xq, h16* __restrict__ ccast,
    h16* __restrict__ SN, h16* __restrict__ ST,
    h16* __restrict__ ktq, float* __restrict__ Dacc)
{
    __shared__ float sm[3*64*68];            // 52,224 B
    const int tid = threadIdx.x;

    if (blockIdx.x < 32) {
        const int layer = blockIdx.x;
        float* la = sm;
        float* kc = sm + 64*68;
        float* kn = sm + 2*64*68;
        const float* k0 = (layer == 0) ? B0 : (Bl + (size_t)(layer-1)*4096);
        const float* Aw = Ast + (size_t)layer*4096;
        for (int e = tid; e < 4096; e += 256) {
            int rr = e >> 6, cc = e & 63;
            kc[rr*68 + cc] = k0[e];
            la[rr*68 + cc] = Aw[e];
        }
        __syncthreads();
        const int r0 = (tid >> 4) << 2;
        const int c0 = (tid & 15) << 2;
        for (int j = 0; j < 16; j++) {
            if (j > 0) {
                __syncthreads();             // prior slice-writes read kc/kn
                float acc[4][4] = {};
                for (int k = 0; k < 64; k++) {
                    float a0 = la[(r0+0)*68 + k];
                    float a1 = la[(r0+1)*68 + k];
                    float a2 = la[(r0+2)*68 + k];
                    float a3 = la[(r0+3)*68 + k];
                    f32x4 bv = *(const f32x4*)&kc[k*68 + c0];
                    #pragma unroll
                    for (int jj = 0; jj < 4; jj++) {
                        acc[0][jj] += a0*bv[jj]; acc[1][jj] += a1*bv[jj];
                        acc[2][jj] += a2*bv[jj]; acc[3][jj] += a3*bv[jj];
                    }
                }
                #pragma unroll
                for (int i2 = 0; i2 < 4; i2++) {
                    f32x4 o; o[0]=acc[i2][0]; o[1]=acc[i2][1]; o[2]=acc[i2][2]; o[3]=acc[i2][3];
                    *(f32x4*)&kn[(r0+i2)*68 + c0] = o;
                }
                __syncthreads();
                float* tmp = kc; kc = kn; kn = tmp;
            }
            size_t base = (size_t)(layer*16 + j)*4096;
            for (int e = tid; e < 4096; e += 256) {
                int n = e >> 6, m = e & 63;
                float v = kc[n*68 + m];
                SN[base + e]          = (h16)v;
                ST[base + m*64 + n]   = (h16)v;
            }
        }
        return;
    }

    // prep section (512 blocks), int4 units
    const int s1 = 256;          // xq[0] pad (2048 h16)
    const int s2 = 65536;        // u cast (524288)
    const int s3 = 1792;         // xq[1..7] pads (7*2048)
    const int s4 = 16384;        // ccast (131072)
    const int s5 = 131072;       // ktq zero (1,048,576 h16)
    const int s6 = 262144;       // Dacc zero (1,048,576 f32)
    const int total = s1+s2+s3+s4+s5+s6;     // 477,184
    const int4 z4 = make_int4(0,0,0,0);
    for (int e0 = (blockIdx.x - 32)*256 + tid; e0 < total; e0 += 512*256) {
        int e = e0;
        if (e < s1) { *(int4*)&xq[e*8] = z4; continue; }
        e -= s1;
        if (e < s2) {
            int el = e*8;
            f32x4 f0 = *(const f32x4*)&u[el];
            f32x4 f1 = *(const f32x4*)&u[el+4];
            h16 ov[8];
            #pragma unroll
            for (int j = 0; j < 4; j++) { ov[j] = (h16)f0[j]; ov[4+j] = (h16)f1[j]; }
            *(int4*)&xq[PAD*NO + el] = *(int4*)&ov[0];
            continue;
        }
        e -= s2;
        if (e < s3) {
            int b = e >> 8, off = (e & 255)*8;
            *(int4*)&xq[(size_t)(b+1)*PB2 + off] = z4;
            continue;
        }
        e -= s3;
        if (e < s4) {
            int el = e*8;
            f32x4 f0 = *(const f32x4*)&Cst[el];
            f32x4 f1 = *(const f32x4*)&Cst[el+4];
            h16 ov[8];
            #pragma unroll
            for (int j = 0; j < 4; j++) { ov[j] = (h16)f0[j]; ov[4+j] = (h16)f1[j]; }
            *(int4*)&ccast[el] = *(int4*)&ov[0];
            continue;
        }
        e -= s4;
        if (e < s5) { *(int4*)&ktq[e*8] = z4; continue; }
        e -= s5;
        *(int4*)&Dacc[e*4] = z4;
    }
}

// ---- compose helper: acc += X(64x64 natural) * Y^T(stored [col][k]) --------
__device__ __forceinline__ void comp_mm(const h16* __restrict__ X,
                                        const h16* __restrict__ Y,
                                        int wv, int r, int q, f32x4 acc[4])
{
    h16x8 a0 = *(const h16x8*)(X + (wv*16 + r)*64 + q*8);
    h16x8 a1 = *(const h16x8*)(X + (wv*16 + r)*64 + 32 + q*8);
    #pragma unroll
    for (int c = 0; c < 4; c++) {
        h16x8 b0 = *(const h16x8*)(Y + (c*16 + r)*64 + q*8);
        h16x8 b1 = *(const h16x8*)(Y + (c*16 + r)*64 + 32 + q*8);
        acc[c] = MFMA16(a0, b0, acc[c]);
        acc[c] = MFMA16(a1, b1, acc[c]);
    }
}
// C/D layout: element (row = wv*16 + q*4 + g4, col = c*16 + r).

// ---- compose2: P2T[g][m2] = (sum_j T^{4g+1}_j T^{4g}_{m2-j})^T, m2=0..30 ----
// plus D1: Dacc[g][j] += C_{4g} * T^{4g}_j, j=0..15.
__global__ __launch_bounds__(256) void compose2(
    const h16* __restrict__ SN, const h16* __restrict__ ST,
    const h16* __restrict__ cc, h16* __restrict__ P2T,
    float* __restrict__ Dacc)
{
    const int tid = threadIdx.x, wv = tid>>6, lane = tid&63, r = lane&15, q = lane>>4;
    f32x4 acc[4] = {};
    int bid = blockIdx.x;
    if (bid < 248) {
        int g = bid / 31, m2 = bid % 31;
        int j0 = m2 > 15 ? m2 - 15 : 0;
        int j1 = m2 < 15 ? m2 : 15;
        const h16* X = SN + ((size_t)(4*g+1)*16 + j0)*4096;
        const h16* Y = ST + ((size_t)(4*g)*16 + (m2 - j0))*4096;
        for (int it = 0; it <= j1 - j0; ++it) {
            comp_mm(X, Y, wv, r, q, acc);
            X += 4096; Y -= 4096;
        }
        h16* o = P2T + ((size_t)g*31 + m2)*4096;
        #pragma unroll
        for (int c = 0; c < 4; c++)
            #pragma unroll
            for (int g4 = 0; g4 < 4; g4++)
                o[(c*16+r)*64 + wv*16 + q*4 + g4] = (h16)acc[c][g4];
    } else {
        int idx = bid - 248, g = idx >> 4, j = idx & 15;
        comp_mm(cc + (size_t)(4*g)*4096, ST + ((size_t)(4*g)*16 + j)*4096, wv, r, q, acc);
        float* Dd = Dacc + ((size_t)g*32 + j)*4096;
        #pragma unroll
        for (int c = 0; c < 4; c++)
            #pragma unroll
            for (int g4 = 0; g4 < 4; g4++)
                atomicAdd(&Dd[(wv*16 + q*4 + g4)*64 + c*16 + r], acc[c][g4]);
    }
}

// ---- compose3: P3T[g][m3] = (sum_j T^{4g+2}_j P2_{m3-j})^T, m3=0..29 -------
// plus D2: Dacc[g][m2+1] += C_{4g+1} * P2_{m2}, m2=0..30.
__global__ __launch_bounds__(256) void compose3(
    const h16* __restrict__ SN, const h16* __restrict__ cc,
    const h16* __restrict__ P2T, h16* __restrict__ P3T,
    float* __restrict__ Dacc)
{
    const int tid = threadIdx.x, wv = tid>>6, lane = tid&63, r = lane&15, q = lane>>4;
    f32x4 acc[4] = {};
    int bid = blockIdx.x;
    if (bid < 240) {
        int g = bid / 30, m3 = bid % 30;
        int j1 = m3 < 15 ? m3 : 15;
        const h16* X = SN + ((size_t)(4*g+2)*16)*4096;
        const h16* Y = P2T + ((size_t)g*31 + m3)*4096;
        for (int it = 0; it <= j1; ++it) {
            comp_mm(X, Y, wv, r, q, acc);
            X += 4096; Y -= 4096;
        }
        h16* o = P3T + ((size_t)g*30 + m3)*4096;
        #pragma unroll
        for (int c = 0; c < 4; c++)
            #pragma unroll
            for (int g4 = 0; g4 < 4; g4++)
                o[(c*16+r)*64 + wv*16 + q*4 + g4] = (h16)acc[c][g4];
    } else {
        int idx = bid - 240, g = idx / 31, m2 = idx % 31;
        comp_mm(cc + (size_t)(4*g+1)*4096, P2T + ((size_t)g*31 + m2)*4096, wv, r, q, acc);
        float* Dd = Dacc + ((size_t)g*32 + m2 + 1)*4096;
        #pragma unroll
        for (int c = 0; c < 4; c++)
            #pragma unroll
            for (int g4 = 0; g4 < 4; g4++)
                atomicAdd(&Dd[(wv*16 + q*4 + g4)*64 + c*16 + r], acc[c][g4]);
    }
}

// ---- compose4: Q[g]_{m4} = sum_j T^{4g+3}_j P3_{m4-j}, m4=0..28 ------------
// writes ktq natural at off = 28-m4; also D4: Dacc[g][m4+3] += C_{4g+3}*Q_{m4}
// (via LDS transpose). plus D3: Dacc[g][m3+2] += C_{4g+2} * P3_{m3}, m3=0..29.
__global__ __launch_bounds__(256) void compose4(
    const h16* __restrict__ SN, const h16* __restrict__ cc,
    const h16* __restrict__ P3T, h16* __restrict__ ktq,
    float* __restrict__ Dacc)
{
    __shared__ h16 ldsT[64*72];
    const int tid = threadIdx.x, wv = tid>>6, lane = tid&63, r = lane&15, q = lane>>4;
    f32x4 acc[4] = {};
    int bid = blockIdx.x;
    if (bid < 232) {
        int g = bid / 29, m4 = bid % 29;
        int j1 = m4 < 15 ? m4 : 15;
        const h16* X = SN + ((size_t)(4*g+3)*16)*4096;
        const h16* Y = P3T + ((size_t)g*30 + m4)*4096;
        for (int it = 0; it <= j1; ++it) {
            comp_mm(X, Y, wv, r, q, acc);
            X += 4096; Y -= 4096;
        }
        // ktq natural [n][off*64+m], off = 28 - m4
        h16* kq = ktq + (size_t)g*131072 + (size_t)(28 - m4)*64;
        #pragma unroll
        for (int c = 0; c < 4; c++)
            #pragma unroll
            for (int g4 = 0; g4 < 4; g4++) {
                h16 v = (h16)acc[c][g4];
                kq[(size_t)(wv*16 + q*4 + g4)*KQ + c*16 + r] = v;
                ldsT[(c*16+r)*72 + wv*16 + q*4 + g4] = v;
            }
        __syncthreads();
        // D4 = C_{4g+3} * Q_{m4}
        f32x4 acc2[4] = {};
        const h16* Xc = cc + (size_t)(4*g+3)*4096;
        h16x8 a0 = *(const h16x8*)(Xc + (wv*16 + r)*64 + q*8);
        h16x8 a1 = *(const h16x8*)(Xc + (wv*16 + r)*64 + 32 + q*8);
        #pragma unroll
        for (int c = 0; c < 4; c++) {
            h16x8 b0 = *(const h16x8*)(&ldsT[(c*16+r)*72 + q*8]);
            h16x8 b1 = *(const h16x8*)(&ldsT[(c*16+r)*72 + 32 + q*8]);
            acc2[c] = MFMA16(a0, b0, acc2[c]);
            acc2[c] = MFMA16(a1, b1, acc2[c]);
        }
        float* Dd = Dacc + ((size_t)g*32 + m4 + 3)*4096;
        #pragma unroll
        for (int c = 0; c < 4; c++)
            #pragma unroll
            for (int g4 = 0; g4 < 4; g4++)
                atomicAdd(&Dd[(wv*16 + q*4 + g4)*64 + c*16 + r], acc2[c][g4]);
    } else {
        int idx = bid - 232, g = idx / 30, m3 = idx % 30;
        comp_mm(cc + (size_t)(4*g+2)*4096, P3T + ((size_t)g*30 + m3)*4096, wv, r, q, acc);
        float* Dd = Dacc + ((size_t)g*32 + m3 + 2)*4096;
        #pragma unroll
        for (int c = 0; c < 4; c++)
            #pragma unroll
            for (int g4 = 0; g4 < 4; g4++)
                atomicAdd(&Dd[(wv*16 + q*4 + g4)*64 + c*16 + r], acc[c][g4]);
    }
}

// ---- castD: Dacc f32 -> ktd f16 [g][y][(31-do)*64+m] -----------------------
__global__ __launch_bounds__(256) void castD(const float* __restrict__ Dacc,
                                             h16* __restrict__ ktd)
{
    const int total4 = 8*32*4096/4;     // 262,144
    for (int idx4 = blockIdx.x*256 + threadIdx.x; idx4 < total4; idx4 += 256*256) {
        int idx = idx4 << 2;
        int gdo = idx >> 12;
        int g = gdo >> 5, dd = gdo & 31;
        int rem = idx & 4095;
        int y = rem >> 6, m = rem & 63;
        f32x4 f = *(const f32x4*)&Dacc[idx];
        h16 o4[4];
        #pragma unroll
        for (int t = 0; t < 4; t++) o4[t] = (h16)f[t];
        *(int2*)&ktd[(size_t)g*131072 + (size_t)y*KQ + (31 - dd)*64 + m] = *(int2*)&o4[0];
    }
}

// ---- stage: one quad. M=64 rows/block, grid 128, 512 threads ---------------
// waves 0-3: state (ktq, split-K4); waves 4-7: y (ktd, split-K4).
template<int WRST>
__global__ __launch_bounds__(512) void stage(
    const h16* __restrict__ pin, h16* __restrict__ pout,
    const h16* __restrict__ ktqg, const h16* __restrict__ ktdg,
    float* __restrict__ out, int first)
{
    __shared__ __align__(16) h16   win[96*72];       // 13,824 B
    __shared__ __align__(16) float red[4*32*68];     // 34,816 B
    const int tid = threadIdx.x;
    const size_t t0 = (size_t)blockIdx.x * 64;

    for (int e = tid; e < 96*8; e += 512) {
        int rr = e >> 3, cc = e & 7;
        *(int4*)&win[rr*72 + cc*8] = *(const int4*)&pin[(t0 + rr)*64 + cc*8];
    }
    __syncthreads();

    const int wv = tid >> 6, lane = tid & 63, r = lane & 15, q = lane >> 4;
    const int half = wv >> 2, kq = wv & 3;
    const bool active = WRST || (half == 1);
    f32x4 acc[4][4] = {};
    if (active) {
        const h16* kb = half ? ktdg : ktqg;
        const h16* abase = &win[(r + kq*8)*72 + q*8];
        const h16* bbase = kb + (size_t)r*KQ + kq*512 + q*8;
#define LDA(s, ls) (*(const h16x8*)(abase + ((s)*16 + ((ls)>>1))*72 + ((ls)&1)*32))
#define LDB(c, ls) (*(const h16x8*)(bbase + (size_t)(c)*(16*KQ) + (ls)*32))
        h16x8 a[2][4], b[2][4];
        #pragma unroll
        for (int sl = 0; sl < 2; sl++) {
            #pragma unroll
            for (int s = 0; s < 4; s++) a[sl][s] = LDA(s, sl);
            #pragma unroll
            for (int c = 0; c < 4; c++) b[sl][c] = LDB(c, sl);
        }
        #pragma unroll
        for (int ls = 0; ls < 16; ls++) {
            h16x8 ca[4], cb[4];
            #pragma unroll
            for (int s = 0; s < 4; s++) ca[s] = a[ls&1][s];
            #pragma unroll
            for (int c = 0; c < 4; c++) cb[c] = b[ls&1][c];
            if (ls < 14) {
                #pragma unroll
                for (int s = 0; s < 4; s++) a[ls&1][s] = LDA(s, ls+2);
                #pragma unroll
                for (int c = 0; c < 4; c++) b[ls&1][c] = LDB(c, ls+2);
            }
            #pragma unroll
            for (int s = 0; s < 4; s++)
                #pragma unroll
                for (int c = 0; c < 4; c++)
                    acc[s][c] = MFMA16(ca[s], cb[c], acc[s][c]);
        }
#undef LDA
#undef LDB
    }

    const int rh = half * (2*32*68);
    #pragma unroll
    for (int ch = 0; ch < 2; ch++) {
        __syncthreads();
        if (active && kq >= 2) {
            float* myred = red + rh + (kq-2)*(32*68);
            #pragma unroll
            for (int s2 = 0; s2 < 2; s2++)
                #pragma unroll
                for (int c = 0; c < 4; c++)
                    #pragma unroll
                    for (int g4 = 0; g4 < 4; g4++)
                        myred[(s2*16 + q*4 + g4)*68 + c*16 + r] = acc[ch*2+s2][c][g4];
        }
        __syncthreads();
        if (active && kq < 2) {
            float* myred = red + rh + kq*(32*68);
            #pragma unroll
            for (int s2 = 0; s2 < 2; s2++)
                #pragma unroll
                for (int c = 0; c < 4; c++)
                    #pragma unroll
                    for (int g4 = 0; g4 < 4; g4++)
                        myred[(s2*16 + q*4 + g4)*68 + c*16 + r] += acc[ch*2+s2][c][g4];
        }
        __syncthreads();
        if (WRST && tid < 256) {
            int orow = tid >> 3, cb2 = (tid & 7) << 3;
            f32x4 u0 = *(const f32x4*)&red[orow*68 + cb2];
            f32x4 u1 = *(const f32x4*)&red[orow*68 + cb2 + 4];
            f32x4 v0 = *(const f32x4*)&red[32*68 + orow*68 + cb2];
            f32x4 v1 = *(const f32x4*)&red[32*68 + orow*68 + cb2 + 4];
            u0 += v0; u1 += v1;
            h16 ov[8];
            #pragma unroll
            for (int j = 0; j < 4; j++) { ov[j] = (h16)u0[j]; ov[4+j] = (h16)u1[j]; }
            *(int4*)&pout[(PAD + t0 + ch*32 + orow)*64 + cb2] = *(int4*)&ov[0];
        }
        if (tid >= 256) {
            int t2 = tid - 256;
            int orow = t2 >> 3, cb2 = (t2 & 7) << 3;
            const float* base = red + 2*32*68;
            f32x4 u0 = *(const f32x4*)&base[orow*68 + cb2];
            f32x4 u1 = *(const f32x4*)&base[orow*68 + cb2 + 4];
            f32x4 v0 = *(const f32x4*)&base[32*68 + orow*68 + cb2];
            f32x4 v1 = *(const f32x4*)&base[32*68 + orow*68 + cb2 + 4];
            u0 += v0; u1 += v1;
            float* op = out + (t0 + ch*32 + orow)*64 + cb2;
            if (first) {
                *(f32x4*)op = u0; *(f32x4*)(op+4) = u1;
            } else {
                f32x4 o0 = *(f32x4*)op, o1 = *(f32x4*)(op+4);
                o0 += u0; o1 += u1;
                *(f32x4*)op = o0; *(f32x4*)(op+4) = o1;
            }
        }
    }
}

extern "C" void kernel_launch(void* const* d_in, const int* in_sizes, int n_in,
                              void* d_out, int out_size, void* d_ws, size_t ws_size,
                              hipStream_t stream)
{
    const float* u   = (const float*)d_in[0];
    const float* Ast = (const float*)d_in[1];
    const float* B0  = (const float*)d_in[2];
    const float* Bl  = (const float*)d_in[3];
    const float* Cst = (const float*)d_in[4];
    float* out = (float*)d_out;
    (void)in_sizes; (void)n_in; (void)out_size; (void)ws_size;

    char* ws = (char*)d_ws;
    h16*   xq    = (h16*)ws;                               // 8 x PB2 = 8,421,376 B
    h16*   ccast = (h16*)(ws + 8421376);                   //   262,144 B
    h16*   SN    = (h16*)(ws + 8683520);                   // 4,194,304 B
    h16*   ST    = (h16*)(ws + 12877824);                  // 4,194,304 B
    h16*   P2T   = (h16*)(ws + 17072128);                  // 2,031,616 B
    h16*   P3T   = (h16*)(ws + 19103744);                  // 1,966,080 B
    h16*   ktq   = (h16*)(ws + 21069824);                  // 2,097,152 B
    h16*   ktd   = (h16*)(ws + 23166976);                  // 2,097,152 B
    float* Dacc  = (float*)(ws + 25264128);                // 4,194,304 B

    prep_build<<<544, 256, 0, stream>>>(u, B0, Bl, Cst, Ast, xq, ccast, SN, ST, ktq, Dacc);
    compose2<<<376, 256, 0, stream>>>(SN, ST, ccast, P2T, Dacc);
    compose3<<<488, 256, 0, stream>>>(SN, ccast, P2T, P3T, Dacc);
    compose4<<<472, 256, 0, stream>>>(SN, ccast, P3T, ktq, Dacc);
    castD<<<256, 256, 0, stream>>>(Dacc, ktd);
    for (int g = 0; g < 7; g++) {
        stage<1><<<128, 512, 0, stream>>>(xq + (size_t)g*PB2, xq + (size_t)(g+1)*PB2,
                                          ktq + (size_t)g*131072, ktd + (size_t)g*131072,
                                          out, g == 0);
    }
    stage<0><<<128, 512, 0, stream>>>(xq + (size_t)7*PB2, xq,
                                      ktq + (size_t)7*131072, ktd + (size_t)7*131072,
                                      out, 0);
}

// Round 11
// 319.664 us; speedup vs baseline: 1.3319x; 1.0875x over previous
//
#include <hip/hip_runtime.h>

// HierarchicalLTI2: 32-layer cascade of 64-dim LTI blocks, T=8192.
// R12 resubmit (prior run died to container infra; kernel never measured).
// R11 structure (4-layer FIR composition, taps d<=32, y folded via D) with:
//  (1) prep_build ST/SN slice writes vectorized (was scalar 2B stride-128B
//      scatter ~27us); transpose read from LDS + int4 stores.
//  (2) stage: M=32 tiles, grid 256 (R11 ran grid 128 = half the CUs idle).
// Serial phases: prep_build | compose2 | compose3 | compose4 | castD | 8 stage.

#define LYR 32
#define NO  64
#define TSEQ 8192
#define PAD 32
#define PR2 (TSEQ+PAD)            // 8224
#define PB2 ((size_t)PR2*NO)      // 526336 elems (h16)
#define KQ  2048                  // stage K = 32 taps * 64

typedef _Float16 h16;
typedef _Float16 h16x8 __attribute__((ext_vector_type(8)));
typedef float    f32x4 __attribute__((ext_vector_type(4)));

#define MFMA16(a,b,c) __builtin_amdgcn_mfma_f32_16x16x32_f16((a),(b),(c),0,0,0)

// ---- prep_build -------------------------------------------------------------
// blocks 0..31: layer singles T^(l)_j = A^j B (f32 chain in LDS), cast to
//   SN[l][j][n][m] (natural) and ST[l][j][m][n] (transposed), j=0..15.
// blocks 32..543: zero xq pads, cast u -> xq[0], cast C -> ccast,
//   zero ktq, zero Dacc.
__global__ __launch_bounds__(256) void prep_build(
    const float* __restrict__ u, const float* __restrict__ B0,
    const float* __restrict__ Bl, const float* __restrict__ Cst,
    const float* __restrict__ Ast,
    h16* __restrict__ xq, h16* __restrict__ ccast,
    h16* __restrict__ SN, h16* __restrict__ ST,
    h16* __restrict__ ktq, float* __restrict__ Dacc)
{
    __shared__ float sm[3*64*68];            // 52,224 B
    const int tid = threadIdx.x;

    if (blockIdx.x < 32) {
        const int layer = blockIdx.x;
        float* la = sm;
        float* kc = sm + 64*68;
        float* kn = sm + 2*64*68;
        const float* k0 = (layer == 0) ? B0 : (Bl + (size_t)(layer-1)*4096);
        const float* Aw = Ast + (size_t)layer*4096;
        for (int e = tid; e < 4096; e += 256) {
            int rr = e >> 6, cc = e & 63;
            kc[rr*68 + cc] = k0[e];
            la[rr*68 + cc] = Aw[e];
        }
        __syncthreads();
        const int r0 = (tid >> 4) << 2;
        const int c0 = (tid & 15) << 2;
        for (int j = 0; j < 16; j++) {
            if (j > 0) {
                __syncthreads();             // prior slice-writes done reading
                float acc[4][4] = {};
                for (int k = 0; k < 64; k++) {
                    float a0 = la[(r0+0)*68 + k];
                    float a1 = la[(r0+1)*68 + k];
                    float a2 = la[(r0+2)*68 + k];
                    float a3 = la[(r0+3)*68 + k];
                    f32x4 bv = *(const f32x4*)&kc[k*68 + c0];
                    #pragma unroll
                    for (int jj = 0; jj < 4; jj++) {
                        acc[0][jj] += a0*bv[jj]; acc[1][jj] += a1*bv[jj];
                        acc[2][jj] += a2*bv[jj]; acc[3][jj] += a3*bv[jj];
                    }
                }
                #pragma unroll
                for (int i2 = 0; i2 < 4; i2++) {
                    f32x4 o; o[0]=acc[i2][0]; o[1]=acc[i2][1]; o[2]=acc[i2][2]; o[3]=acc[i2][3];
                    *(f32x4*)&kn[(r0+i2)*68 + c0] = o;
                }
                __syncthreads();
                float* tmp = kc; kc = kn; kn = tmp;
            }
            // vectorized slice write: SN natural + ST transposed (int4 stores)
            size_t base = (size_t)(layer*16 + j)*4096;
            for (int e8 = tid; e8 < 512; e8 += 256) {
                int n = e8 >> 3, m0 = (e8 & 7) << 3;
                h16 o[8];
                #pragma unroll
                for (int t = 0; t < 8; t++) o[t] = (h16)kc[n*68 + m0 + t];
                *(int4*)&SN[base + (size_t)n*64 + m0] = *(int4*)&o[0];
                h16 o2[8];
                #pragma unroll
                for (int t = 0; t < 8; t++) o2[t] = (h16)kc[(m0+t)*68 + n];
                *(int4*)&ST[base + (size_t)n*64 + m0] = *(int4*)&o2[0];
            }
        }
        return;
    }

    // prep section (512 blocks), int4 units
    const int s1 = 256;          // xq[0] pad (2048 h16)
    const int s2 = 65536;        // u cast (524288)
    const int s3 = 1792;         // xq[1..7] pads (7*2048)
    const int s4 = 16384;        // ccast (131072)
    const int s5 = 131072;       // ktq zero (1,048,576 h16)
    const int s6 = 262144;       // Dacc zero (1,048,576 f32)
    const int total = s1+s2+s3+s4+s5+s6;     // 477,184
    const int4 z4 = make_int4(0,0,0,0);
    for (int e0 = (blockIdx.x - 32)*256 + tid; e0 < total; e0 += 512*256) {
        int e = e0;
        if (e < s1) { *(int4*)&xq[e*8] = z4; continue; }
        e -= s1;
        if (e < s2) {
            int el = e*8;
            f32x4 f0 = *(const f32x4*)&u[el];
            f32x4 f1 = *(const f32x4*)&u[el+4];
            h16 ov[8];
            #pragma unroll
            for (int j = 0; j < 4; j++) { ov[j] = (h16)f0[j]; ov[4+j] = (h16)f1[j]; }
            *(int4*)&xq[PAD*NO + el] = *(int4*)&ov[0];
            continue;
        }
        e -= s2;
        if (e < s3) {
            int b = e >> 8, off = (e & 255)*8;
            *(int4*)&xq[(size_t)(b+1)*PB2 + off] = z4;
            continue;
        }
        e -= s3;
        if (e < s4) {
            int el = e*8;
            f32x4 f0 = *(const f32x4*)&Cst[el];
            f32x4 f1 = *(const f32x4*)&Cst[el+4];
            h16 ov[8];
            #pragma unroll
            for (int j = 0; j < 4; j++) { ov[j] = (h16)f0[j]; ov[4+j] = (h16)f1[j]; }
            *(int4*)&ccast[el] = *(int4*)&ov[0];
            continue;
        }
        e -= s4;
        if (e < s5) { *(int4*)&ktq[e*8] = z4; continue; }
        e -= s5;
        *(int4*)&Dacc[e*4] = z4;
    }
}

// ---- compose helper: acc += X(64x64 natural) * Y^T(stored [col][k]) --------
__device__ __forceinline__ void comp_mm(const h16* __restrict__ X,
                                        const h16* __restrict__ Y,
                                        int wv, int r, int q, f32x4 acc[4])
{
    h16x8 a0 = *(const h16x8*)(X + (wv*16 + r)*64 + q*8);
    h16x8 a1 = *(const h16x8*)(X + (wv*16 + r)*64 + 32 + q*8);
    #pragma unroll
    for (int c = 0; c < 4; c++) {
        h16x8 b0 = *(const h16x8*)(Y + (c*16 + r)*64 + q*8);
        h16x8 b1 = *(const h16x8*)(Y + (c*16 + r)*64 + 32 + q*8);
        acc[c] = MFMA16(a0, b0, acc[c]);
        acc[c] = MFMA16(a1, b1, acc[c]);
    }
}
// C/D layout: element (row = wv*16 + q*4 + g4, col = c*16 + r).

// ---- compose2: P2T[g][m2] = (sum_j T^{4g+1}_j T^{4g}_{m2-j})^T, m2=0..30 ----
// plus D1: Dacc[g][j] += C_{4g} * T^{4g}_j, j=0..15.
__global__ __launch_bounds__(256) void compose2(
    const h16* __restrict__ SN, const h16* __restrict__ ST,
    const h16* __restrict__ cc, h16* __restrict__ P2T,
    float* __restrict__ Dacc)
{
    const int tid = threadIdx.x, wv = tid>>6, lane = tid&63, r = lane&15, q = lane>>4;
    f32x4 acc[4] = {};
    int bid = blockIdx.x;
    if (bid < 248) {
        int g = bid / 31, m2 = bid % 31;
        int j0 = m2 > 15 ? m2 - 15 : 0;
        int j1 = m2 < 15 ? m2 : 15;
        const h16* X = SN + ((size_t)(4*g+1)*16 + j0)*4096;
        const h16* Y = ST + ((size_t)(4*g)*16 + (m2 - j0))*4096;
        for (int it = 0; it <= j1 - j0; ++it) {
            comp_mm(X, Y, wv, r, q, acc);
            X += 4096; Y -= 4096;
        }
        h16* o = P2T + ((size_t)g*31 + m2)*4096;
        #pragma unroll
        for (int c = 0; c < 4; c++)
            #pragma unroll
            for (int g4 = 0; g4 < 4; g4++)
                o[(c*16+r)*64 + wv*16 + q*4 + g4] = (h16)acc[c][g4];
    } else {
        int idx = bid - 248, g = idx >> 4, j = idx & 15;
        comp_mm(cc + (size_t)(4*g)*4096, ST + ((size_t)(4*g)*16 + j)*4096, wv, r, q, acc);
        float* Dd = Dacc + ((size_t)g*32 + j)*4096;
        #pragma unroll
        for (int c = 0; c < 4; c++)
            #pragma unroll
            for (int g4 = 0; g4 < 4; g4++)
                atomicAdd(&Dd[(wv*16 + q*4 + g4)*64 + c*16 + r], acc[c][g4]);
    }
}

// ---- compose3: P3T[g][m3] = (sum_j T^{4g+2}_j P2_{m3-j})^T, m3=0..29 -------
// plus D2: Dacc[g][m2+1] += C_{4g+1} * P2_{m2}, m2=0..30.
__global__ __launch_bounds__(256) void compose3(
    const h16* __restrict__ SN, const h16* __restrict__ cc,
    const h16* __restrict__ P2T, h16* __restrict__ P3T,
    float* __restrict__ Dacc)
{
    const int tid = threadIdx.x, wv = tid>>6, lane = tid&63, r = lane&15, q = lane>>4;
    f32x4 acc[4] = {};
    int bid = blockIdx.x;
    if (bid < 240) {
        int g = bid / 30, m3 = bid % 30;
        int j1 = m3 < 15 ? m3 : 15;
        const h16* X = SN + ((size_t)(4*g+2)*16)*4096;
        const h16* Y = P2T + ((size_t)g*31 + m3)*4096;
        for (int it = 0; it <= j1; ++it) {
            comp_mm(X, Y, wv, r, q, acc);
            X += 4096; Y -= 4096;
        }
        h16* o = P3T + ((size_t)g*30 + m3)*4096;
        #pragma unroll
        for (int c = 0; c < 4; c++)
            #pragma unroll
            for (int g4 = 0; g4 < 4; g4++)
                o[(c*16+r)*64 + wv*16 + q*4 + g4] = (h16)acc[c][g4];
    } else {
        int idx = bid - 240, g = idx / 31, m2 = idx % 31;
        comp_mm(cc + (size_t)(4*g+1)*4096, P2T + ((size_t)g*31 + m2)*4096, wv, r, q, acc);
        float* Dd = Dacc + ((size_t)g*32 + m2 + 1)*4096;
        #pragma unroll
        for (int c = 0; c < 4; c++)
            #pragma unroll
            for (int g4 = 0; g4 < 4; g4++)
                atomicAdd(&Dd[(wv*16 + q*4 + g4)*64 + c*16 + r], acc[c][g4]);
    }
}

// ---- compose4: Q[g]_{m4} = sum_j T^{4g+3}_j P3_{m4-j}, m4=0..28 ------------
// writes ktq natural at off = 28-m4; also D4: Dacc[g][m4+3] += C_{4g+3}*Q_{m4}
// (via LDS transpose). plus D3: Dacc[g][m3+2] += C_{4g+2} * P3_{m3}, m3=0..29.
__global__ __launch_bounds__(256) void compose4(
    const h16* __restrict__ SN, const h16* __restrict__ cc,
    const h16* __restrict__ P3T, h16* __restrict__ ktq,
    float* __restrict__ Dacc)
{
    __shared__ h16 ldsT[64*72];
    const int tid = threadIdx.x, wv = tid>>6, lane = tid&63, r = lane&15, q = lane>>4;
    f32x4 acc[4] = {};
    int bid = blockIdx.x;
    if (bid < 232) {
        int g = bid / 29, m4 = bid % 29;
        int j1 = m4 < 15 ? m4 : 15;
        const h16* X = SN + ((size_t)(4*g+3)*16)*4096;
        const h16* Y = P3T + ((size_t)g*30 + m4)*4096;
        for (int it = 0; it <= j1; ++it) {
            comp_mm(X, Y, wv, r, q, acc);
            X += 4096; Y -= 4096;
        }
        h16* kq = ktq + (size_t)g*131072 + (size_t)(28 - m4)*64;
        #pragma unroll
        for (int c = 0; c < 4; c++)
            #pragma unroll
            for (int g4 = 0; g4 < 4; g4++) {
                h16 v = (h16)acc[c][g4];
                kq[(size_t)(wv*16 + q*4 + g4)*KQ + c*16 + r] = v;
                ldsT[(c*16+r)*72 + wv*16 + q*4 + g4] = v;
            }
        __syncthreads();
        f32x4 acc2[4] = {};
        const h16* Xc = cc + (size_t)(4*g+3)*4096;
        h16x8 a0 = *(const h16x8*)(Xc + (wv*16 + r)*64 + q*8);
        h16x8 a1 = *(const h16x8*)(Xc + (wv*16 + r)*64 + 32 + q*8);
        #pragma unroll
        for (int c = 0; c < 4; c++) {
            h16x8 b0 = *(const h16x8*)(&ldsT[(c*16+r)*72 + q*8]);
            h16x8 b1 = *(const h16x8*)(&ldsT[(c*16+r)*72 + 32 + q*8]);
            acc2[c] = MFMA16(a0, b0, acc2[c]);
            acc2[c] = MFMA16(a1, b1, acc2[c]);
        }
        float* Dd = Dacc + ((size_t)g*32 + m4 + 3)*4096;
        #pragma unroll
        for (int c = 0; c < 4; c++)
            #pragma unroll
            for (int g4 = 0; g4 < 4; g4++)
                atomicAdd(&Dd[(wv*16 + q*4 + g4)*64 + c*16 + r], acc2[c][g4]);
    } else {
        int idx = bid - 232, g = idx / 30, m3 = idx % 30;
        comp_mm(cc + (size_t)(4*g+2)*4096, P3T + ((size_t)g*30 + m3)*4096, wv, r, q, acc);
        float* Dd = Dacc + ((size_t)g*32 + m3 + 2)*4096;
        #pragma unroll
        for (int c = 0; c < 4; c++)
            #pragma unroll
            for (int g4 = 0; g4 < 4; g4++)
                atomicAdd(&Dd[(wv*16 + q*4 + g4)*64 + c*16 + r], acc[c][g4]);
    }
}

// ---- castD: Dacc f32 -> ktd f16 [g][y][(31-do)*64+m] -----------------------
__global__ __launch_bounds__(256) void castD(const float* __restrict__ Dacc,
                                             h16* __restrict__ ktd)
{
    const int total4 = 8*32*4096/4;     // 262,144
    for (int idx4 = blockIdx.x*256 + threadIdx.x; idx4 < total4; idx4 += 256*256) {
        int idx = idx4 << 2;
        int gdo = idx >> 12;
        int g = gdo >> 5, dd = gdo & 31;
        int rem = idx & 4095;
        int y = rem >> 6, m = rem & 63;
        f32x4 f = *(const f32x4*)&Dacc[idx];
        h16 o4[4];
        #pragma unroll
        for (int t = 0; t < 4; t++) o4[t] = (h16)f[t];
        *(int2*)&ktd[(size_t)g*131072 + (size_t)y*KQ + (31 - dd)*64 + m] = *(int2*)&o4[0];
    }
}

// ---- stage: one quad. M=32 rows/block, grid 256 (full machine), 512 thr ----
// waves 0-3: state (ktq, split-K4); waves 4-7: y (ktd, split-K4).
template<int WRST>
__global__ __launch_bounds__(512) void stage(
    const h16* __restrict__ pin, h16* __restrict__ pout,
    const h16* __restrict__ ktqg, const h16* __restrict__ ktdg,
    float* __restrict__ out, int first)
{
    __shared__ __align__(16) h16   win[64*72];       //  9,216 B
    __shared__ __align__(16) float red[4*32*68];     // 34,816 B
    const int tid = threadIdx.x;
    const size_t t0 = (size_t)blockIdx.x * 32;

    {   // window: padded rows t0 .. t0+63 (out row w needs rows w..w+31)
        int rr = tid >> 3, cc = tid & 7;
        *(int4*)&win[rr*72 + cc*8] = *(const int4*)&pin[(t0 + rr)*64 + cc*8];
    }
    __syncthreads();

    const int wv = tid >> 6, lane = tid & 63, r = lane & 15, q = lane >> 4;
    const int half = wv >> 2, kq = wv & 3;
    const bool active = WRST || (half == 1);
    f32x4 acc[2][4] = {};
    if (active) {
        const h16* kb = half ? ktdg : ktqg;
        const h16* abase = &win[(r + kq*8)*72 + q*8];
        const h16* bbase = kb + (size_t)r*KQ + kq*512 + q*8;
#define LDA(s, ls) (*(const h16x8*)(abase + ((s)*16 + ((ls)>>1))*72 + ((ls)&1)*32))
#define LDB(c, ls) (*(const h16x8*)(bbase + (size_t)(c)*(16*KQ) + (ls)*32))
        h16x8 a[2][2], b[2][4];
        #pragma unroll
        for (int sl = 0; sl < 2; sl++) {
            #pragma unroll
            for (int s = 0; s < 2; s++) a[sl][s] = LDA(s, sl);
            #pragma unroll
            for (int c = 0; c < 4; c++) b[sl][c] = LDB(c, sl);
        }
        #pragma unroll
        for (int ls = 0; ls < 16; ls++) {
            h16x8 ca[2], cb[4];
            #pragma unroll
            for (int s = 0; s < 2; s++) ca[s] = a[ls&1][s];
            #pragma unroll
            for (int c = 0; c < 4; c++) cb[c] = b[ls&1][c];
            if (ls < 14) {
                #pragma unroll
                for (int s = 0; s < 2; s++) a[ls&1][s] = LDA(s, ls+2);
                #pragma unroll
                for (int c = 0; c < 4; c++) b[ls&1][c] = LDB(c, ls+2);
            }
            #pragma unroll
            for (int s = 0; s < 2; s++)
                #pragma unroll
                for (int c = 0; c < 4; c++)
                    acc[s][c] = MFMA16(ca[s], cb[c], acc[s][c]);
        }
#undef LDA
#undef LDB
    }

    const int rh = half * (2*32*68);
    __syncthreads();
    if (active && kq >= 2) {
        float* myred = red + rh + (kq-2)*(32*68);
        #pragma unroll
        for (int s2 = 0; s2 < 2; s2++)
            #pragma unroll
            for (int c = 0; c < 4; c++)
                #pragma unroll
                for (int g4 = 0; g4 < 4; g4++)
                    myred[(s2*16 + q*4 + g4)*68 + c*16 + r] = acc[s2][c][g4];
    }
    __syncthreads();
    if (active && kq < 2) {
        float* myred = red + rh + kq*(32*68);
        #pragma unroll
        for (int s2 = 0; s2 < 2; s2++)
            #pragma unroll
            for (int c = 0; c < 4; c++)
                #pragma unroll
                for (int g4 = 0; g4 < 4; g4++)
                    myred[(s2*16 + q*4 + g4)*68 + c*16 + r] += acc[s2][c][g4];
    }
    __syncthreads();
    if (WRST && tid < 256) {
        int orow = tid >> 3, cb2 = (tid & 7) << 3;
        f32x4 u0 = *(const f32x4*)&red[orow*68 + cb2];
        f32x4 u1 = *(const f32x4*)&red[orow*68 + cb2 + 4];
        f32x4 v0 = *(const f32x4*)&red[32*68 + orow*68 + cb2];
        f32x4 v1 = *(const f32x4*)&red[32*68 + orow*68 + cb2 + 4];
        u0 += v0; u1 += v1;
        h16 ov[8];
        #pragma unroll
        for (int j = 0; j < 4; j++) { ov[j] = (h16)u0[j]; ov[4+j] = (h16)u1[j]; }
        *(int4*)&pout[(PAD + t0 + orow)*64 + cb2] = *(int4*)&ov[0];
    }
    if (tid >= 256) {
        int t2 = tid - 256;
        int orow = t2 >> 3, cb2 = (t2 & 7) << 3;
        const float* base = red + 2*32*68;
        f32x4 u0 = *(const f32x4*)&base[orow*68 + cb2];
        f32x4 u1 = *(const f32x4*)&base[orow*68 + cb2 + 4];
        f32x4 v0 = *(const f32x4*)&base[32*68 + orow*68 + cb2];
        f32x4 v1 = *(const f32x4*)&base[32*68 + orow*68 + cb2 + 4];
        u0 += v0; u1 += v1;
        float* op = out + (t0 + orow)*64 + cb2;
        if (first) {
            *(f32x4*)op = u0; *(f32x4*)(op+4) = u1;
        } else {
            f32x4 o0 = *(f32x4*)op, o1 = *(f32x4*)(op+4);
            o0 += u0; o1 += u1;
            *(f32x4*)op = o0; *(f32x4*)(op+4) = o1;
        }
    }
}

extern "C" void kernel_launch(void* const* d_in, const int* in_sizes, int n_in,
                              void* d_out, int out_size, void* d_ws, size_t ws_size,
                              hipStream_t stream)
{
    const float* u   = (const float*)d_in[0];
    const float* Ast = (const float*)d_in[1];
    const float* B0  = (const float*)d_in[2];
    const float* Bl  = (const float*)d_in[3];
    const float* Cst = (const float*)d_in[4];
    float* out = (float*)d_out;
    (void)in_sizes; (void)n_in; (void)out_size; (void)ws_size;

    char* ws = (char*)d_ws;
    h16*   xq    = (h16*)ws;                               // 8 x PB2 = 8,421,376 B
    h16*   ccast = (h16*)(ws + 8421376);                   //   262,144 B
    h16*   SN    = (h16*)(ws + 8683520);                   // 4,194,304 B
    h16*   ST    = (h16*)(ws + 12877824);                  // 4,194,304 B
    h16*   P2T   = (h16*)(ws + 17072128);                  // 2,031,616 B
    h16*   P3T   = (h16*)(ws + 19103744);                  // 1,966,080 B
    h16*   ktq   = (h16*)(ws + 21069824);                  // 2,097,152 B
    h16*   ktd   = (h16*)(ws + 23166976);                  // 2,097,152 B
    float* Dacc  = (float*)(ws + 25264128);                // 4,194,304 B

    prep_build<<<544, 256, 0, stream>>>(u, B0, Bl, Cst, Ast, xq, ccast, SN, ST, ktq, Dacc);
    compose2<<<376, 256, 0, stream>>>(SN, ST, ccast, P2T, Dacc);
    compose3<<<488, 256, 0, stream>>>(SN, ccast, P2T, P3T, Dacc);
    compose4<<<472, 256, 0, stream>>>(SN, ccast, P3T, ktq, Dacc);
    castD<<<256, 256, 0, stream>>>(Dacc, ktd);
    for (int g = 0; g < 7; g++) {
        stage<1><<<256, 512, 0, stream>>>(xq + (size_t)g*PB2, xq + (size_t)(g+1)*PB2,
                                          ktq + (size_t)g*131072, ktd + (size_t)g*131072,
                                          out, g == 0);
    }
    stage<0><<<256, 512, 0, stream>>>(xq + (size_t)7*PB2, xq,
                                      ktq + (size_t)7*131072, ktd + (size_t)7*131072,
                                      out, 0);
}

// Round 12
// 303.035 us; speedup vs baseline: 1.4050x; 1.0549x over previous
//
#include <hip/hip_runtime.h>

// HierarchicalLTI2: 32-layer cascade of 64-dim LTI blocks, T=8192.
// R13 = R12 (4-layer FIR composition, verified) with:
//  (1) prep_build chain -> MFMA (f16 operands, f32 acc, f32 LDS master);
//      SN written only for l%4!=0, ST only for l%4==0 (what composes read).
//      R12 measured 54.6us, all-VALU serial chain.
//  (2) stage: M=64 per block (two 32-row sub-tiles SHARING B registers),
//      grid 128 -- A/B test of the B-broadcast L2-serialization theory
//      (per-XCD duplicate line requests halve; same FLOPs, same layouts).

#define LYR 32
#define NO  64
#define TSEQ 8192
#define PAD 32
#define PR2 (TSEQ+PAD)            // 8224
#define PB2 ((size_t)PR2*NO)      // 526336 elems (h16)
#define KQ  2048                  // stage K = 32 taps * 64

typedef _Float16 h16;
typedef _Float16 h16x8 __attribute__((ext_vector_type(8)));
typedef float    f32x4 __attribute__((ext_vector_type(4)));

#define MFMA16(a,b,c) __builtin_amdgcn_mfma_f32_16x16x32_f16((a),(b),(c),0,0,0)

// ---- prep_build -------------------------------------------------------------
// blocks 0..31: layer singles T^(l)_j = A^j B via MFMA chain (f16 in, f32 acc,
//   f32 LDS master). Slices cast to SN[l][j] (natural; l%4!=0) or ST[l][j]
//   (transposed; l%4==0), j=0..15.
// blocks 32..543: zero xq pads, cast u -> xq[0], cast C -> ccast,
//   zero ktq, zero Dacc.
__global__ __launch_bounds__(256) void prep_build(
    const float* __restrict__ u, const float* __restrict__ B0,
    const float* __restrict__ Bl, const float* __restrict__ Cst,
    const float* __restrict__ Ast,
    h16* __restrict__ xq, h16* __restrict__ ccast,
    h16* __restrict__ SN, h16* __restrict__ ST,
    h16* __restrict__ ktq, float* __restrict__ Dacc)
{
    __shared__ __align__(16) h16   Ah[64*72];     //  9,216 B (A f16, natural)
    __shared__ __align__(16) h16   kT[64*72];     //  9,216 B (K^T f16)
    __shared__ __align__(16) float kf[64*68];     // 17,408 B (K f32 master)
    const int tid = threadIdx.x;

    if (blockIdx.x < 32) {
        const int layer = blockIdx.x;
        const bool wantST = (layer & 3) == 0;     // compose reads ST[4g] only
        const float* k0 = (layer == 0) ? B0 : (Bl + (size_t)(layer-1)*4096);
        const float* Aw = Ast + (size_t)layer*4096;
        // init: Ah (f16 natural), kf = K_0 (f32 natural)
        for (int e8 = tid; e8 < 512; e8 += 256) {
            int n = e8 >> 3, m0 = (e8 & 7) << 3;
            f32x4 a0 = *(const f32x4*)&Aw[n*64 + m0];
            f32x4 a1 = *(const f32x4*)&Aw[n*64 + m0 + 4];
            h16 ah[8];
            #pragma unroll
            for (int t = 0; t < 4; t++) { ah[t] = (h16)a0[t]; ah[4+t] = (h16)a1[t]; }
            *(int4*)&Ah[n*72 + m0] = *(int4*)&ah[0];
            f32x4 b0 = *(const f32x4*)&k0[n*64 + m0];
            f32x4 b1 = *(const f32x4*)&k0[n*64 + m0 + 4];
            *(f32x4*)&kf[n*68 + m0]     = b0;
            *(f32x4*)&kf[n*68 + m0 + 4] = b1;
        }
        __syncthreads();

        const int wv = tid >> 6, lane = tid & 63, r = lane & 15, q = lane >> 4;
        const h16x8 a0 = *(const h16x8*)&Ah[(wv*16 + r)*72 + q*8];
        const h16x8 a1 = *(const h16x8*)&Ah[(wv*16 + r)*72 + 32 + q*8];

        for (int j = 0; j < 16; j++) {
            if (j > 0) {
                // MFMA: K_j = A * K_{j-1} (reads kT, writes kf)
                f32x4 acc[4] = {};
                #pragma unroll
                for (int c = 0; c < 4; c++) {
                    h16x8 b0 = *(const h16x8*)&kT[(c*16 + r)*72 + q*8];
                    h16x8 b1 = *(const h16x8*)&kT[(c*16 + r)*72 + 32 + q*8];
                    acc[c] = MFMA16(a0, b0, acc[c]);
                    acc[c] = MFMA16(a1, b1, acc[c]);
                }
                #pragma unroll
                for (int c = 0; c < 4; c++)
                    #pragma unroll
                    for (int g4 = 0; g4 < 4; g4++)
                        kf[(wv*16 + q*4 + g4)*68 + c*16 + r] = acc[c][g4];
                __syncthreads();
            }
            // slice write from kf (vectorized) + rebuild kT for next step
            size_t base = (size_t)(layer*16 + j)*4096;
            for (int e8 = tid; e8 < 512; e8 += 256) {
                int n = e8 >> 3, m0 = (e8 & 7) << 3;
                f32x4 v0 = *(const f32x4*)&kf[n*68 + m0];
                f32x4 v1 = *(const f32x4*)&kf[n*68 + m0 + 4];
                h16 o[8];
                #pragma unroll
                for (int t = 0; t < 4; t++) { o[t] = (h16)v0[t]; o[4+t] = (h16)v1[t]; }
                if (!wantST)
                    *(int4*)&SN[base + (size_t)n*64 + m0] = *(int4*)&o[0];
                #pragma unroll
                for (int t = 0; t < 8; t++)
                    kT[(m0 + t)*72 + n] = o[t];
                if (wantST) {
                    h16 o2[8];
                    #pragma unroll
                    for (int t = 0; t < 8; t++) o2[t] = (h16)kf[(m0 + t)*68 + n];
                    *(int4*)&ST[base + (size_t)n*64 + m0] = *(int4*)&o2[0];
                }
            }
            __syncthreads();
        }
        return;
    }

    // prep section (512 blocks), int4 units
    const int s1 = 256;          // xq[0] pad (2048 h16)
    const int s2 = 65536;        // u cast (524288)
    const int s3 = 1792;         // xq[1..7] pads (7*2048)
    const int s4 = 16384;        // ccast (131072)
    const int s5 = 131072;       // ktq zero (1,048,576 h16)
    const int s6 = 262144;       // Dacc zero (1,048,576 f32)
    const int total = s1+s2+s3+s4+s5+s6;     // 477,184
    const int4 z4 = make_int4(0,0,0,0);
    for (int e0 = (blockIdx.x - 32)*256 + tid; e0 < total; e0 += 512*256) {
        int e = e0;
        if (e < s1) { *(int4*)&xq[e*8] = z4; continue; }
        e -= s1;
        if (e < s2) {
            int el = e*8;
            f32x4 f0 = *(const f32x4*)&u[el];
            f32x4 f1 = *(const f32x4*)&u[el+4];
            h16 ov[8];
            #pragma unroll
            for (int j = 0; j < 4; j++) { ov[j] = (h16)f0[j]; ov[4+j] = (h16)f1[j]; }
            *(int4*)&xq[PAD*NO + el] = *(int4*)&ov[0];
            continue;
        }
        e -= s2;
        if (e < s3) {
            int b = e >> 8, off = (e & 255)*8;
            *(int4*)&xq[(size_t)(b+1)*PB2 + off] = z4;
            continue;
        }
        e -= s3;
        if (e < s4) {
            int el = e*8;
            f32x4 f0 = *(const f32x4*)&Cst[el];
            f32x4 f1 = *(const f32x4*)&Cst[el+4];
            h16 ov[8];
            #pragma unroll
            for (int j = 0; j < 4; j++) { ov[j] = (h16)f0[j]; ov[4+j] = (h16)f1[j]; }
            *(int4*)&ccast[el] = *(int4*)&ov[0];
            continue;
        }
        e -= s4;
        if (e < s5) { *(int4*)&ktq[e*8] = z4; continue; }
        e -= s5;
        *(int4*)&Dacc[e*4] = z4;
    }
}

// ---- compose helper: acc += X(64x64 natural) * Y^T(stored [col][k]) --------
__device__ __forceinline__ void comp_mm(const h16* __restrict__ X,
                                        const h16* __restrict__ Y,
                                        int wv, int r, int q, f32x4 acc[4])
{
    h16x8 a0 = *(const h16x8*)(X + (wv*16 + r)*64 + q*8);
    h16x8 a1 = *(const h16x8*)(X + (wv*16 + r)*64 + 32 + q*8);
    #pragma unroll
    for (int c = 0; c < 4; c++) {
        h16x8 b0 = *(const h16x8*)(Y + (c*16 + r)*64 + q*8);
        h16x8 b1 = *(const h16x8*)(Y + (c*16 + r)*64 + 32 + q*8);
        acc[c] = MFMA16(a0, b0, acc[c]);
        acc[c] = MFMA16(a1, b1, acc[c]);
    }
}
// C/D layout: element (row = wv*16 + q*4 + g4, col = c*16 + r).

// ---- compose2: P2T[g][m2] = (sum_j T^{4g+1}_j T^{4g}_{m2-j})^T, m2=0..30 ----
// plus D1: Dacc[g][j] += C_{4g} * T^{4g}_j, j=0..15.
__global__ __launch_bounds__(256) void compose2(
    const h16* __restrict__ SN, const h16* __restrict__ ST,
    const h16* __restrict__ cc, h16* __restrict__ P2T,
    float* __restrict__ Dacc)
{
    const int tid = threadIdx.x, wv = tid>>6, lane = tid&63, r = lane&15, q = lane>>4;
    f32x4 acc[4] = {};
    int bid = blockIdx.x;
    if (bid < 248) {
        int g = bid / 31, m2 = bid % 31;
        int j0 = m2 > 15 ? m2 - 15 : 0;
        int j1 = m2 < 15 ? m2 : 15;
        const h16* X = SN + ((size_t)(4*g+1)*16 + j0)*4096;
        const h16* Y = ST + ((size_t)(4*g)*16 + (m2 - j0))*4096;
        for (int it = 0; it <= j1 - j0; ++it) {
            comp_mm(X, Y, wv, r, q, acc);
            X += 4096; Y -= 4096;
        }
        h16* o = P2T + ((size_t)g*31 + m2)*4096;
        #pragma unroll
        for (int c = 0; c < 4; c++)
            #pragma unroll
            for (int g4 = 0; g4 < 4; g4++)
                o[(c*16+r)*64 + wv*16 + q*4 + g4] = (h16)acc[c][g4];
    } else {
        int idx = bid - 248, g = idx >> 4, j = idx & 15;
        comp_mm(cc + (size_t)(4*g)*4096, ST + ((size_t)(4*g)*16 + j)*4096, wv, r, q, acc);
        float* Dd = Dacc + ((size_t)g*32 + j)*4096;
        #pragma unroll
        for (int c = 0; c < 4; c++)
            #pragma unroll
            for (int g4 = 0; g4 < 4; g4++)
                atomicAdd(&Dd[(wv*16 + q*4 + g4)*64 + c*16 + r], acc[c][g4]);
    }
}

// ---- compose3: P3T[g][m3] = (sum_j T^{4g+2}_j P2_{m3-j})^T, m3=0..29 -------
// plus D2: Dacc[g][m2+1] += C_{4g+1} * P2_{m2}, m2=0..30.
__global__ __launch_bounds__(256) void compose3(
    const h16* __restrict__ SN, const h16* __restrict__ cc,
    const h16* __restrict__ P2T, h16* __restrict__ P3T,
    float* __restrict__ Dacc)
{
    const int tid = threadIdx.x, wv = tid>>6, lane = tid&63, r = lane&15, q = lane>>4;
    f32x4 acc[4] = {};
    int bid = blockIdx.x;
    if (bid < 240) {
        int g = bid / 30, m3 = bid % 30;
        int j1 = m3 < 15 ? m3 : 15;
        const h16* X = SN + ((size_t)(4*g+2)*16)*4096;
        const h16* Y = P2T + ((size_t)g*31 + m3)*4096;
        for (int it = 0; it <= j1; ++it) {
            comp_mm(X, Y, wv, r, q, acc);
            X += 4096; Y -= 4096;
        }
        h16* o = P3T + ((size_t)g*30 + m3)*4096;
        #pragma unroll
        for (int c = 0; c < 4; c++)
            #pragma unroll
            for (int g4 = 0; g4 < 4; g4++)
                o[(c*16+r)*64 + wv*16 + q*4 + g4] = (h16)acc[c][g4];
    } else {
        int idx = bid - 240, g = idx / 31, m2 = idx % 31;
        comp_mm(cc + (size_t)(4*g+1)*4096, P2T + ((size_t)g*31 + m2)*4096, wv, r, q, acc);
        float* Dd = Dacc + ((size_t)g*32 + m2 + 1)*4096;
        #pragma unroll
        for (int c = 0; c < 4; c++)
            #pragma unroll
            for (int g4 = 0; g4 < 4; g4++)
                atomicAdd(&Dd[(wv*16 + q*4 + g4)*64 + c*16 + r], acc[c][g4]);
    }
}

// ---- compose4: Q[g]_{m4} = sum_j T^{4g+3}_j P3_{m4-j}, m4=0..28 ------------
// writes ktq natural at off = 28-m4; also D4: Dacc[g][m4+3] += C_{4g+3}*Q_{m4}
// (via LDS transpose). plus D3: Dacc[g][m3+2] += C_{4g+2} * P3_{m3}, m3=0..29.
__global__ __launch_bounds__(256) void compose4(
    const h16* __restrict__ SN, const h16* __restrict__ cc,
    const h16* __restrict__ P3T, h16* __restrict__ ktq,
    float* __restrict__ Dacc)
{
    __shared__ h16 ldsT[64*72];
    const int tid = threadIdx.x, wv = tid>>6, lane = tid&63, r = lane&15, q = lane>>4;
    f32x4 acc[4] = {};
    int bid = blockIdx.x;
    if (bid < 232) {
        int g = bid / 29, m4 = bid % 29;
        int j1 = m4 < 15 ? m4 : 15;
        const h16* X = SN + ((size_t)(4*g+3)*16)*4096;
        const h16* Y = P3T + ((size_t)g*30 + m4)*4096;
        for (int it = 0; it <= j1; ++it) {
            comp_mm(X, Y, wv, r, q, acc);
            X += 4096; Y -= 4096;
        }
        h16* kq = ktq + (size_t)g*131072 + (size_t)(28 - m4)*64;
        #pragma unroll
        for (int c = 0; c < 4; c++)
            #pragma unroll
            for (int g4 = 0; g4 < 4; g4++) {
                h16 v = (h16)acc[c][g4];
                kq[(size_t)(wv*16 + q*4 + g4)*KQ + c*16 + r] = v;
                ldsT[(c*16+r)*72 + wv*16 + q*4 + g4] = v;
            }
        __syncthreads();
        f32x4 acc2[4] = {};
        const h16* Xc = cc + (size_t)(4*g+3)*4096;
        h16x8 a0 = *(const h16x8*)(Xc + (wv*16 + r)*64 + q*8);
        h16x8 a1 = *(const h16x8*)(Xc + (wv*16 + r)*64 + 32 + q*8);
        #pragma unroll
        for (int c = 0; c < 4; c++) {
            h16x8 b0 = *(const h16x8*)(&ldsT[(c*16+r)*72 + q*8]);
            h16x8 b1 = *(const h16x8*)(&ldsT[(c*16+r)*72 + 32 + q*8]);
            acc2[c] = MFMA16(a0, b0, acc2[c]);
            acc2[c] = MFMA16(a1, b1, acc2[c]);
        }
        float* Dd = Dacc + ((size_t)g*32 + m4 + 3)*4096;
        #pragma unroll
        for (int c = 0; c < 4; c++)
            #pragma unroll
            for (int g4 = 0; g4 < 4; g4++)
                atomicAdd(&Dd[(wv*16 + q*4 + g4)*64 + c*16 + r], acc2[c][g4]);
    } else {
        int idx = bid - 232, g = idx / 30, m3 = idx % 30;
        comp_mm(cc + (size_t)(4*g+2)*4096, P3T + ((size_t)g*30 + m3)*4096, wv, r, q, acc);
        float* Dd = Dacc + ((size_t)g*32 + m3 + 2)*4096;
        #pragma unroll
        for (int c = 0; c < 4; c++)
            #pragma unroll
            for (int g4 = 0; g4 < 4; g4++)
                atomicAdd(&Dd[(wv*16 + q*4 + g4)*64 + c*16 + r], acc[c][g4]);
    }
}

// ---- castD: Dacc f32 -> ktd f16 [g][y][(31-do)*64+m] -----------------------
__global__ __launch_bounds__(256) void castD(const float* __restrict__ Dacc,
                                             h16* __restrict__ ktd)
{
    const int total4 = 8*32*4096/4;     // 262,144
    for (int idx4 = blockIdx.x*256 + threadIdx.x; idx4 < total4; idx4 += 256*256) {
        int idx = idx4 << 2;
        int gdo = idx >> 12;
        int g = gdo >> 5, dd = gdo & 31;
        int rem = idx & 4095;
        int y = rem >> 6, m = rem & 63;
        f32x4 f = *(const f32x4*)&Dacc[idx];
        h16 o4[4];
        #pragma unroll
        for (int t = 0; t < 4; t++) o4[t] = (h16)f[t];
        *(int2*)&ktd[(size_t)g*131072 + (size_t)y*KQ + (31 - dd)*64 + m] = *(int2*)&o4[0];
    }
}

// ---- stage: one quad. M=64/block (2 sub-tiles sharing B regs), grid 128 ----
// waves 0-3: state (ktq, split-K4); waves 4-7: y (ktd, split-K4).
template<int WRST>
__global__ __launch_bounds__(512) void stage(
    const h16* __restrict__ pin, h16* __restrict__ pout,
    const h16* __restrict__ ktqg, const h16* __restrict__ ktdg,
    float* __restrict__ out, int first)
{
    __shared__ __align__(16) h16   win[96*72];       // 13,824 B
    __shared__ __align__(16) float red[4*32*68];     // 34,816 B
    const int tid = threadIdx.x;
    const size_t t0 = (size_t)blockIdx.x * 64;

    // window: padded rows t0 .. t0+95 (sub-tile st out row w needs w..w+31)
    for (int e = tid; e < 96*8; e += 512) {
        int rr = e >> 3, cc = e & 7;
        *(int4*)&win[rr*72 + cc*8] = *(const int4*)&pin[(t0 + rr)*64 + cc*8];
    }
    __syncthreads();

    const int wv = tid >> 6, lane = tid & 63, r = lane & 15, q = lane >> 4;
    const int half = wv >> 2, kq = wv & 3;
    const bool active = WRST || (half == 1);
    f32x4 acc[2][2][4] = {};                  // [sub-tile][s][c]
    if (active) {
        const h16* kb = half ? ktdg : ktqg;
        const h16* abase = &win[(r + kq*8)*72 + q*8];
        const h16* bbase = kb + (size_t)r*KQ + kq*512 + q*8;
#define LDA(st, s, ls) (*(const h16x8*)(abase + ((st)*32 + (s)*16 + ((ls)>>1))*72 + ((ls)&1)*32))
#define LDB(c, ls) (*(const h16x8*)(bbase + (size_t)(c)*(16*KQ) + (ls)*32))
        h16x8 a[2][2][2], b[2][4];            // a[slot][st][s], b[slot][c]
        #pragma unroll
        for (int sl = 0; sl < 2; sl++) {
            #pragma unroll
            for (int st = 0; st < 2; st++)
                #pragma unroll
                for (int s = 0; s < 2; s++) a[sl][st][s] = LDA(st, s, sl);
            #pragma unroll
            for (int c = 0; c < 4; c++) b[sl][c] = LDB(c, sl);
        }
        #pragma unroll
        for (int ls = 0; ls < 16; ls++) {
            h16x8 ca[2][2], cb[4];
            #pragma unroll
            for (int st = 0; st < 2; st++)
                #pragma unroll
                for (int s = 0; s < 2; s++) ca[st][s] = a[ls&1][st][s];
            #pragma unroll
            for (int c = 0; c < 4; c++) cb[c] = b[ls&1][c];
            if (ls < 14) {
                #pragma unroll
                for (int st = 0; st < 2; st++)
                    #pragma unroll
                    for (int s = 0; s < 2; s++) a[ls&1][st][s] = LDA(st, s, ls+2);
                #pragma unroll
                for (int c = 0; c < 4; c++) b[ls&1][c] = LDB(c, ls+2);
            }
            #pragma unroll
            for (int st = 0; st < 2; st++)
                #pragma unroll
                for (int s = 0; s < 2; s++)
                    #pragma unroll
                    for (int c = 0; c < 4; c++)
                        acc[st][s][c] = MFMA16(ca[st][s], cb[c], acc[st][s][c]);
        }
#undef LDA
#undef LDB
    }

    const int rh = half * (2*32*68);
    #pragma unroll
    for (int st = 0; st < 2; st++) {
        __syncthreads();
        if (active && kq >= 2) {
            float* myred = red + rh + (kq-2)*(32*68);
            #pragma unroll
            for (int s2 = 0; s2 < 2; s2++)
                #pragma unroll
                for (int c = 0; c < 4; c++)
                    #pragma unroll
                    for (int g4 = 0; g4 < 4; g4++)
                        myred[(s2*16 + q*4 + g4)*68 + c*16 + r] = acc[st][s2][c][g4];
        }
        __syncthreads();
        if (active && kq < 2) {
            float* myred = red + rh + kq*(32*68);
            #pragma unroll
            for (int s2 = 0; s2 < 2; s2++)
                #pragma unroll
                for (int c = 0; c < 4; c++)
                    #pragma unroll
                    for (int g4 = 0; g4 < 4; g4++)
                        myred[(s2*16 + q*4 + g4)*68 + c*16 + r] += acc[st][s2][c][g4];
        }
        __syncthreads();
        if (WRST && tid < 256) {
            int orow = tid >> 3, cb2 = (tid & 7) << 3;
            f32x4 u0 = *(const f32x4*)&red[orow*68 + cb2];
            f32x4 u1 = *(const f32x4*)&red[orow*68 + cb2 + 4];
            f32x4 v0 = *(const f32x4*)&red[32*68 + orow*68 + cb2];
            f32x4 v1 = *(const f32x4*)&red[32*68 + orow*68 + cb2 + 4];
            u0 += v0; u1 += v1;
            h16 ov[8];
            #pragma unroll
            for (int j = 0; j < 4; j++) { ov[j] = (h16)u0[j]; ov[4+j] = (h16)u1[j]; }
            *(int4*)&pout[(PAD + t0 + st*32 + orow)*64 + cb2] = *(int4*)&ov[0];
        }
        if (tid >= 256) {
            int t2 = tid - 256;
            int orow = t2 >> 3, cb2 = (t2 & 7) << 3;
            const float* base = red + 2*32*68;
            f32x4 u0 = *(const f32x4*)&base[orow*68 + cb2];
            f32x4 u1 = *(const f32x4*)&base[orow*68 + cb2 + 4];
            f32x4 v0 = *(const f32x4*)&base[32*68 + orow*68 + cb2];
            f32x4 v1 = *(const f32x4*)&base[32*68 + orow*68 + cb2 + 4];
            u0 += v0; u1 += v1;
            float* op = out + (t0 + st*32 + orow)*64 + cb2;
            if (first) {
                *(f32x4*)op = u0; *(f32x4*)(op+4) = u1;
            } else {
                f32x4 o0 = *(f32x4*)op, o1 = *(f32x4*)(op+4);
                o0 += u0; o1 += u1;
                *(f32x4*)op = o0; *(f32x4*)(op+4) = o1;
            }
        }
    }
}

extern "C" void kernel_launch(void* const* d_in, const int* in_sizes, int n_in,
                              void* d_out, int out_size, void* d_ws, size_t ws_size,
                              hipStream_t stream)
{
    const float* u   = (const float*)d_in[0];
    const float* Ast = (const float*)d_in[1];
    const float* B0  = (const float*)d_in[2];
    const float* Bl  = (const float*)d_in[3];
    const float* Cst = (const float*)d_in[4];
    float* out = (float*)d_out;
    (void)in_sizes; (void)n_in; (void)out_size; (void)ws_size;

    char* ws = (char*)d_ws;
    h16*   xq    = (h16*)ws;                               // 8 x PB2 = 8,421,376 B
    h16*   ccast = (h16*)(ws + 8421376);                   //   262,144 B
    h16*   SN    = (h16*)(ws + 8683520);                   // 4,194,304 B
    h16*   ST    = (h16*)(ws + 12877824);                  // 4,194,304 B
    h16*   P2T   = (h16*)(ws + 17072128);                  // 2,031,616 B
    h16*   P3T   = (h16*)(ws + 19103744);                  // 1,966,080 B
    h16*   ktq   = (h16*)(ws + 21069824);                  // 2,097,152 B
    h16*   ktd   = (h16*)(ws + 23166976);                  // 2,097,152 B
    float* Dacc  = (float*)(ws + 25264128);                // 4,194,304 B

    prep_build<<<544, 256, 0, stream>>>(u, B0, Bl, Cst, Ast, xq, ccast, SN, ST, ktq, Dacc);
    compose2<<<376, 256, 0, stream>>>(SN, ST, ccast, P2T, Dacc);
    compose3<<<488, 256, 0, stream>>>(SN, ccast, P2T, P3T, Dacc);
    compose4<<<472, 256, 0, stream>>>(SN, ccast, P3T, ktq, Dacc);
    castD<<<256, 256, 0, stream>>>(Dacc, ktd);
    for (int g = 0; g < 7; g++) {
        stage<1><<<TSEQ/64, 512, 0, stream>>>(xq + (size_t)g*PB2, xq + (size_t)(g+1)*PB2,
                                              ktq + (size_t)g*131072, ktd + (size_t)g*131072,
                                              out, g == 0);
    }
    stage<0><<<TSEQ/64, 512, 0, stream>>>(xq + (size_t)7*PB2, xq,
                                          ktq + (size_t)7*131072, ktd + (size_t)7*131072,
                                          out, 0);
}